// Round 1
// baseline (267.505 us; speedup 1.0000x reference)
//
#include <hip/hip_runtime.h>
#include <math.h>

typedef _Float16 f16;
typedef __attribute__((ext_vector_type(8))) _Float16 f16x8;
typedef __attribute__((ext_vector_type(4))) _Float16 f16x4;
typedef __attribute__((ext_vector_type(4))) float f32x4;

#define NSEQ 4096
#define DIN 1024
#define DOUT 1024

// async global->LDS, 16B per lane; LDS dest must be wave-uniform base + lane*16
__device__ __forceinline__ void load16(const void* g, void* l) {
    __builtin_amdgcn_global_load_lds(
        (const __attribute__((address_space(1))) unsigned int*)g,
        (__attribute__((address_space(3))) unsigned int*)l, 16, 0, 0);
}

// C[M,N] = scale * (A[M,K] @ B[N,K]^T).  A,B f16; OutT = f16 or float.
// 128x128 tile, BK=32, 4 waves in 2x2, each wave 64x64 via 4x4 MFMA 16x16x32.
template <typename OutT>
__global__ __launch_bounds__(256, 2)
void gemm_bt(const f16* __restrict__ A, const f16* __restrict__ B,
             OutT* __restrict__ C, int M, int N, int K,
             int lda, int ldb, int ldc, float scale,
             long bStrideZ, long cStrideZ)
{
    B += (long)blockIdx.z * bStrideZ;
    C += (long)blockIdx.z * cStrideZ;
    __shared__ f16 As[128 * 32];
    __shared__ f16 Bs[128 * 32];
    const int t    = threadIdx.x;
    const int lane = t & 63;
    const int wave = t >> 6;
    const int wm   = (wave >> 1) * 64;
    const int wn   = (wave & 1) * 64;
    const int tile_m = blockIdx.y * 128;
    const int tile_n = blockIdx.x * 128;
    const int quad = lane >> 4;
    const int l16  = lane & 15;
    // staging map: thread t sweep s covers LDS elems (s*256+t)*8 .. +8
    // == tile row (s*64 + t/4), cols (t%4)*8 .. +8
    const int srow = t >> 2;
    const int scol = (t & 3) * 8;

    f32x4 acc[4][4];
#pragma unroll
    for (int i = 0; i < 4; i++)
#pragma unroll
        for (int j = 0; j < 4; j++)
            acc[i][j] = (f32x4){0.f, 0.f, 0.f, 0.f};

    const f16* Ab = A + (long)(tile_m + srow) * lda + scol;
    const f16* Bb = B + (long)(tile_n + srow) * ldb + scol;
    f16* Asd = As + t * 8;
    f16* Bsd = Bs + t * 8;

    for (int k0 = 0; k0 < K; k0 += 32) {
        load16(Ab + k0, Asd);
        load16(Ab + (long)64 * lda + k0, Asd + 2048);
        load16(Bb + k0, Bsd);
        load16(Bb + (long)64 * ldb + k0, Bsd + 2048);
        __syncthreads();  // compiler drains vmcnt(0) before barrier
        f16x8 a[4], b[4];
#pragma unroll
        for (int i = 0; i < 4; i++)
            a[i] = *(const f16x8*)(As + (wm + i * 16 + l16) * 32 + quad * 8);
#pragma unroll
        for (int j = 0; j < 4; j++)
            b[j] = *(const f16x8*)(Bs + (wn + j * 16 + l16) * 32 + quad * 8);
#pragma unroll
        for (int i = 0; i < 4; i++)
#pragma unroll
            for (int j = 0; j < 4; j++)
                acc[i][j] = __builtin_amdgcn_mfma_f32_16x16x32_f16(
                    a[i], b[j], acc[i][j], 0, 0, 0);
        __syncthreads();
    }
    // epilogue: D row = quad*4 + reg, col = lane&15  (verified m89/m91 layout)
#pragma unroll
    for (int i = 0; i < 4; i++)
#pragma unroll
        for (int j = 0; j < 4; j++)
#pragma unroll
            for (int r = 0; r < 4; r++) {
                int row = tile_m + wm + i * 16 + quad * 4 + r;
                int col = tile_n + wn + j * 16 + l16;
                C[(long)row * ldc + col] = (OutT)(acc[i][j][r] * scale);
            }
}

__global__ void cvt_f16(const float* __restrict__ x, f16* __restrict__ y) {
    int i = (blockIdx.x * 256 + threadIdx.x) * 4;
    f32x4 v = *(const f32x4*)(x + i);
    f16x4 o;
    o.x = (f16)v.x; o.y = (f16)v.y; o.z = (f16)v.z; o.w = (f16)v.w;
    *(f16x4*)(y + i) = o;
}

// W[z]: fp32 [in=1024][out=1024] -> Wt[z]: f16 [out=1024][in=1024]
__global__ void transpose_w3(const float* __restrict__ W0, const float* __restrict__ W1,
                             const float* __restrict__ W2, f16* __restrict__ Wt) {
    __shared__ f16 tile[64][65];
    const float* W = blockIdx.z == 0 ? W0 : (blockIdx.z == 1 ? W1 : W2);
    f16* O = Wt + (long)blockIdx.z * DIN * DOUT;
    int r0 = blockIdx.y * 64;   // in-dim
    int c0 = blockIdx.x * 64;   // out-dim
    int tx = threadIdx.x & 63, ty = threadIdx.x >> 6;
#pragma unroll
    for (int i = 0; i < 16; i++)
        tile[ty + i * 4][tx] = (f16)W[(long)(r0 + ty + i * 4) * DOUT + c0 + tx];
    __syncthreads();
#pragma unroll
    for (int i = 0; i < 16; i++)
        O[(long)(c0 + ty + i * 4) * DIN + r0 + tx] = tile[tx][ty + i * 4];
}

// V: f16 [4096][1024] -> Vt: f16 [1024][4096]
__global__ void transpose_v(const f16* __restrict__ V, f16* __restrict__ Vt) {
    __shared__ f16 tile[64][65];
    int r0 = blockIdx.y * 64;   // seq
    int c0 = blockIdx.x * 64;   // d
    int tx = threadIdx.x & 63, ty = threadIdx.x >> 6;
#pragma unroll
    for (int i = 0; i < 16; i++)
        tile[ty + i * 4][tx] = V[(long)(r0 + ty + i * 4) * DOUT + c0 + tx];
    __syncthreads();
#pragma unroll
    for (int i = 0; i < 16; i++)
        Vt[(long)(c0 + ty + i * 4) * NSEQ + r0 + tx] = tile[tx][ty + i * 4];
}

// row softmax over 4096 fp32, writes f16 P in-place over the row's first 8KB.
// Safe: all reads complete before first __syncthreads(); writes come after.
__global__ __launch_bounds__(256)
void softmax_inplace(float* __restrict__ S) {
    const int t = threadIdx.x;
    float* Srow = S + (long)blockIdx.x * NSEQ;
    f16* Prow = (f16*)Srow;
    float v[16];
#pragma unroll
    for (int c = 0; c < 4; c++) {
        f32x4 x = *(const f32x4*)(Srow + (c * 256 + t) * 4);
        v[c * 4 + 0] = x.x; v[c * 4 + 1] = x.y;
        v[c * 4 + 2] = x.z; v[c * 4 + 3] = x.w;
    }
    int lane = t & 63, wave = t >> 6;
    float m = -1e30f;
#pragma unroll
    for (int i = 0; i < 16; i++) m = fmaxf(m, v[i]);
#pragma unroll
    for (int off = 32; off; off >>= 1) m = fmaxf(m, __shfl_xor(m, off, 64));
    __shared__ float redm[4];
    if (lane == 0) redm[wave] = m;
    __syncthreads();
    m = fmaxf(fmaxf(redm[0], redm[1]), fmaxf(redm[2], redm[3]));
    float s = 0.f;
#pragma unroll
    for (int i = 0; i < 16; i++) { v[i] = __expf(v[i] - m); s += v[i]; }
#pragma unroll
    for (int off = 32; off; off >>= 1) s += __shfl_xor(s, off, 64);
    __shared__ float reds[4];
    if (lane == 0) reds[wave] = s;
    __syncthreads();
    s = reds[0] + reds[1] + reds[2] + reds[3];
    float inv = 1.f / s;
#pragma unroll
    for (int c = 0; c < 4; c++) {
        f16x4 o;
        o.x = (f16)(v[c * 4 + 0] * inv);
        o.y = (f16)(v[c * 4 + 1] * inv);
        o.z = (f16)(v[c * 4 + 2] * inv);
        o.w = (f16)(v[c * 4 + 3] * inv);
        *(f16x4*)(Prow + (c * 256 + t) * 4) = o;
    }
}

extern "C" void kernel_launch(void* const* d_in, const int* in_sizes, int n_in,
                              void* d_out, int out_size, void* d_ws, size_t ws_size,
                              hipStream_t stream) {
    const float* x  = (const float*)d_in[0];
    const float* Wq = (const float*)d_in[1];
    const float* Wk = (const float*)d_in[2];
    const float* Wv = (const float*)d_in[3];
    float* out = (float*)d_out;
    char* ws = (char*)d_ws;
    const size_t MB = 1ull << 20;
    // layout (102 MB total): xb [0,8) reused as Vt after GEMM1
    f16* xb = (f16*)(ws);              // 8 MB, x in f16
    f16* Wt = (f16*)(ws + 8 * MB);     // 6 MB, 3x [out,in] f16
    f16* Qb = (f16*)(ws + 14 * MB);    // 8 MB
    f16* Kb = (f16*)(ws + 22 * MB);    // 8 MB
    f16* Vb = (f16*)(ws + 30 * MB);    // 8 MB
    f16* Vt = (f16*)(ws);              // 8 MB (xb dead after GEMM1)
    float* S = (float*)(ws + 38 * MB); // 64 MB; P f16 aliased in-place

    cvt_f16<<<4096, 256, 0, stream>>>(x, xb);
    transpose_w3<<<dim3(16, 16, 3), 256, 0, stream>>>(Wq, Wk, Wv, Wt);
    // Q|K|V = xb @ Wt^T  (z picks weight + output)
    gemm_bt<f16><<<dim3(8, 32, 3), 256, 0, stream>>>(
        xb, Wt, Qb, NSEQ, DOUT, DIN, DIN, DIN, DOUT, 1.0f,
        (long)DIN * DOUT, (long)NSEQ * DOUT);
    transpose_v<<<dim3(16, 64), 256, 0, stream>>>(Vb, Vt);
    // S = Q @ K^T * (1/sqrt(1024))
    gemm_bt<float><<<dim3(32, 32, 1), 256, 0, stream>>>(
        Qb, Kb, S, NSEQ, NSEQ, DOUT, DOUT, DOUT, NSEQ, 0.03125f, 0, 0);
    softmax_inplace<<<4096, 256, 0, stream>>>(S);
    // out = P @ Vt^T ; P rows at stride 8192 f16 (aliased over fp32 S rows)
    gemm_bt<float><<<dim3(8, 32, 1), 256, 0, stream>>>(
        (const f16*)S, Vt, out, NSEQ, DOUT, NSEQ, 2 * NSEQ, NSEQ, DOUT, 1.0f, 0, 0);
}

// Round 2
// 236.144 us; speedup vs baseline: 1.1328x; 1.1328x over previous
//
#include <hip/hip_runtime.h>
#include <math.h>

typedef _Float16 f16;
typedef __attribute__((ext_vector_type(8))) _Float16 f16x8;
typedef __attribute__((ext_vector_type(4))) _Float16 f16x4;
typedef __attribute__((ext_vector_type(4))) float f32x4;

#define NSEQ 4096
#define DIN 1024
#define DOUT 1024

// async global->LDS, 16B per lane; LDS dest must be wave-uniform base + lane*16
__device__ __forceinline__ void load16(const void* g, void* l) {
    __builtin_amdgcn_global_load_lds(
        (const __attribute__((address_space(1))) unsigned int*)g,
        (__attribute__((address_space(3))) unsigned int*)l, 16, 0, 0);
}

// C[M,N] = scale * (A[M,K] @ B[N,K]^T).  A,B f16; OutT = f16 or float.
// 128x128 tile, BK=64 (two 32-col panels), 4 waves 2x2, 4x4 MFMA 16x16x32.
// XCD patch swizzle: assuming xcd = linear_bid % 8, each XCD's consecutive
// blocks form an 8-wide x 4-tall patch of tiles -> per-XCD L2 working set
// ~3MB (Q/K panels) instead of the whole matrix. Requires gx%8==0, gy%4==0.
template <typename OutT>
__global__ __launch_bounds__(256, 2)
void gemm_bt(const f16* __restrict__ A, const f16* __restrict__ B,
             OutT* __restrict__ C, int M, int N, int K,
             int lda, int ldb, int ldc, float scale,
             long bStrideZ, long cStrideZ)
{
    B += (long)blockIdx.z * bStrideZ;
    C += (long)blockIdx.z * cStrideZ;
    __shared__ f16 As[2 * 128 * 32];
    __shared__ f16 Bs[2 * 128 * 32];

    // ---- XCD patch swizzle (bijective remap of (bx,by)) ----
    int gx = gridDim.x;
    int bid = blockIdx.y * gx + blockIdx.x;
    int xcd = bid & 7, s = bid >> 3;
    int px = s & 7, rest = s >> 3;
    int py = rest & 3, chunk = rest >> 2;
    int pg = xcd + (chunk << 3);          // global patch id
    int pcols = gx >> 3;                  // patches per row (power of 2)
    int lp = 31 - __clz(pcols);
    int bx = ((pg & (pcols - 1)) << 3) + px;
    int by = ((pg >> lp) << 2) + py;

    const int t    = threadIdx.x;
    const int lane = t & 63;
    const int wave = t >> 6;
    const int wm   = (wave >> 1) * 64;
    const int wn   = (wave & 1) * 64;
    const int tile_m = by * 128;
    const int tile_n = bx * 128;
    const int quad = lane >> 4;
    const int l16  = lane & 15;
    // staging map per 32-col panel: thread t covers row t/4, cols (t%4)*8..+8
    const int srow = t >> 2;
    const int scol = (t & 3) * 8;

    f32x4 acc[4][4];
#pragma unroll
    for (int i = 0; i < 4; i++)
#pragma unroll
        for (int j = 0; j < 4; j++)
            acc[i][j] = (f32x4){0.f, 0.f, 0.f, 0.f};

    const f16* Ab = A + (long)(tile_m + srow) * lda + scol;
    const f16* Bb = B + (long)(tile_n + srow) * ldb + scol;
    f16* Asd = As + t * 8;
    f16* Bsd = Bs + t * 8;

    for (int k0 = 0; k0 < K; k0 += 64) {
        // panel 0: cols k0..k0+31 ; panel 1: cols k0+32..k0+63
        load16(Ab + k0, Asd);
        load16(Ab + (long)64 * lda + k0, Asd + 2048);
        load16(Ab + k0 + 32, Asd + 4096);
        load16(Ab + (long)64 * lda + k0 + 32, Asd + 4096 + 2048);
        load16(Bb + k0, Bsd);
        load16(Bb + (long)64 * ldb + k0, Bsd + 2048);
        load16(Bb + k0 + 32, Bsd + 4096);
        load16(Bb + (long)64 * ldb + k0 + 32, Bsd + 4096 + 2048);
        __syncthreads();  // drains vmcnt(0); 32 MFMA/wave per drain now
#pragma unroll
        for (int p = 0; p < 2; p++) {
            f16x8 a[4], b[4];
#pragma unroll
            for (int i = 0; i < 4; i++)
                a[i] = *(const f16x8*)(As + p * 4096 + (wm + i * 16 + l16) * 32 + quad * 8);
#pragma unroll
            for (int j = 0; j < 4; j++)
                b[j] = *(const f16x8*)(Bs + p * 4096 + (wn + j * 16 + l16) * 32 + quad * 8);
#pragma unroll
            for (int i = 0; i < 4; i++)
#pragma unroll
                for (int j = 0; j < 4; j++)
                    acc[i][j] = __builtin_amdgcn_mfma_f32_16x16x32_f16(
                        a[i], b[j], acc[i][j], 0, 0, 0);
        }
        __syncthreads();
    }
    // epilogue: D row = quad*4 + reg, col = lane&15  (verified m89/m91 layout)
#pragma unroll
    for (int i = 0; i < 4; i++)
#pragma unroll
        for (int j = 0; j < 4; j++)
#pragma unroll
            for (int r = 0; r < 4; r++) {
                int row = tile_m + wm + i * 16 + quad * 4 + r;
                int col = tile_n + wn + j * 16 + l16;
                C[(long)row * ldc + col] = (OutT)(acc[i][j][r] * scale);
            }
}

__global__ void cvt_f16(const float* __restrict__ x, f16* __restrict__ y) {
    int i = (blockIdx.x * 256 + threadIdx.x) * 4;
    f32x4 v = *(const f32x4*)(x + i);
    f16x4 o;
    o.x = (f16)v.x; o.y = (f16)v.y; o.z = (f16)v.z; o.w = (f16)v.w;
    *(f16x4*)(y + i) = o;
}

// W[z]: fp32 [in=1024][out=1024] -> Wt[z]: f16 [out=1024][in=1024]
__global__ void transpose_w3(const float* __restrict__ W0, const float* __restrict__ W1,
                             const float* __restrict__ W2, f16* __restrict__ Wt) {
    __shared__ f16 tile[64][65];
    const float* W = blockIdx.z == 0 ? W0 : (blockIdx.z == 1 ? W1 : W2);
    f16* O = Wt + (long)blockIdx.z * DIN * DOUT;
    int r0 = blockIdx.y * 64;   // in-dim
    int c0 = blockIdx.x * 64;   // out-dim
    int tx = threadIdx.x & 63, ty = threadIdx.x >> 6;
#pragma unroll
    for (int i = 0; i < 16; i++)
        tile[ty + i * 4][tx] = (f16)W[(long)(r0 + ty + i * 4) * DOUT + c0 + tx];
    __syncthreads();
#pragma unroll
    for (int i = 0; i < 16; i++)
        O[(long)(c0 + ty + i * 4) * DIN + r0 + tx] = tile[tx][ty + i * 4];
}

// V: f16 [4096][1024] -> Vt: f16 [1024][4096]
__global__ void transpose_v(const f16* __restrict__ V, f16* __restrict__ Vt) {
    __shared__ f16 tile[64][65];
    int r0 = blockIdx.y * 64;   // seq
    int c0 = blockIdx.x * 64;   // d
    int tx = threadIdx.x & 63, ty = threadIdx.x >> 6;
#pragma unroll
    for (int i = 0; i < 16; i++)
        tile[ty + i * 4][tx] = V[(long)(r0 + ty + i * 4) * DOUT + c0 + tx];
    __syncthreads();
#pragma unroll
    for (int i = 0; i < 16; i++)
        Vt[(long)(c0 + ty + i * 4) * NSEQ + r0 + tx] = tile[tx][ty + i * 4];
}

// row softmax over 4096 f16 scores (already scaled), f16 out, in-place.
// Each thread reads/writes only its own 16B chunks -> alias-safe.
__global__ __launch_bounds__(256)
void softmax_f16(f16* __restrict__ S) {
    const int t = threadIdx.x;
    f16* row = S + (long)blockIdx.x * NSEQ;
    float v[16];
    f16x8 x0 = *(const f16x8*)(row + t * 8);
    f16x8 x1 = *(const f16x8*)(row + 2048 + t * 8);
#pragma unroll
    for (int i = 0; i < 8; i++) { v[i] = (float)x0[i]; v[8 + i] = (float)x1[i]; }
    int lane = t & 63, wave = t >> 6;
    float m = -1e30f;
#pragma unroll
    for (int i = 0; i < 16; i++) m = fmaxf(m, v[i]);
#pragma unroll
    for (int off = 32; off; off >>= 1) m = fmaxf(m, __shfl_xor(m, off, 64));
    __shared__ float redm[4];
    if (lane == 0) redm[wave] = m;
    __syncthreads();
    m = fmaxf(fmaxf(redm[0], redm[1]), fmaxf(redm[2], redm[3]));
    float sum = 0.f;
#pragma unroll
    for (int i = 0; i < 16; i++) { v[i] = __expf(v[i] - m); sum += v[i]; }
#pragma unroll
    for (int off = 32; off; off >>= 1) sum += __shfl_xor(sum, off, 64);
    __shared__ float reds[4];
    if (lane == 0) reds[wave] = sum;
    __syncthreads();
    sum = reds[0] + reds[1] + reds[2] + reds[3];
    float inv = 1.f / sum;
    f16x8 o0, o1;
#pragma unroll
    for (int i = 0; i < 8; i++) {
        o0[i] = (f16)(v[i] * inv);
        o1[i] = (f16)(v[8 + i] * inv);
    }
    *(f16x8*)(row + t * 8) = o0;
    *(f16x8*)(row + 2048 + t * 8) = o1;
}

extern "C" void kernel_launch(void* const* d_in, const int* in_sizes, int n_in,
                              void* d_out, int out_size, void* d_ws, size_t ws_size,
                              hipStream_t stream) {
    const float* x  = (const float*)d_in[0];
    const float* Wq = (const float*)d_in[1];
    const float* Wk = (const float*)d_in[2];
    const float* Wv = (const float*)d_in[3];
    float* out = (float*)d_out;
    char* ws = (char*)d_ws;
    const size_t MB = 1ull << 20;
    // layout (70 MB total): xb [0,8) reused as Vt after GEMM1
    f16* xb = (f16*)(ws);              // 8 MB, x in f16
    f16* Wt = (f16*)(ws + 8 * MB);     // 6 MB, 3x [out,in] f16
    f16* Qb = (f16*)(ws + 14 * MB);    // 8 MB
    f16* Kb = (f16*)(ws + 22 * MB);    // 8 MB
    f16* Vb = (f16*)(ws + 30 * MB);    // 8 MB
    f16* Vt = (f16*)(ws);              // 8 MB (xb dead after GEMM1)
    f16* S  = (f16*)(ws + 38 * MB);    // 32 MB f16 scores; P in-place

    cvt_f16<<<4096, 256, 0, stream>>>(x, xb);
    transpose_w3<<<dim3(16, 16, 3), 256, 0, stream>>>(Wq, Wk, Wv, Wt);
    // Q|K|V = xb @ Wt^T  (z picks weight + output)
    gemm_bt<f16><<<dim3(8, 32, 3), 256, 0, stream>>>(
        xb, Wt, Qb, NSEQ, DOUT, DIN, DIN, DIN, DOUT, 1.0f,
        (long)DIN * DOUT, (long)NSEQ * DOUT);
    transpose_v<<<dim3(16, 64), 256, 0, stream>>>(Vb, Vt);
    // S = (Q @ K^T) / 32, stored f16
    gemm_bt<f16><<<dim3(32, 32, 1), 256, 0, stream>>>(
        Qb, Kb, S, NSEQ, NSEQ, DOUT, DOUT, DOUT, NSEQ, 0.03125f, 0, 0);
    softmax_f16<<<4096, 256, 0, stream>>>(S);
    // out = P @ Vt^T
    gemm_bt<float><<<dim3(8, 32, 1), 256, 0, stream>>>(
        S, Vt, out, NSEQ, DOUT, NSEQ, NSEQ, NSEQ, DOUT, 1.0f, 0, 0);
}